// Round 4
// baseline (9343.252 us; speedup 1.0000x reference)
//
#include <hip/hip_runtime.h>
#include <math.h>

#define NN 50000
#define NE 1600000
#define FE 32
#define DF 128
#define NG 512
#define NC 10

// ---------------- int64-vs-int32 index dtype detection ----------------
// Reference declares edge_index/batch as int64. If raw int64 buffers are
// passed, odd 32-bit words of the first 128 entries are all 0 (values <
// 50000, nonnegative). If int32, those words are src indices (nonzero w.h.p.).

__global__ void detect_i64(const unsigned int* __restrict__ w, int* __restrict__ flag) {
    if (threadIdx.x == 0 && blockIdx.x == 0) {
        unsigned int acc = 0;
        for (int i = 0; i < 128; i++) acc |= w[2 * i + 1];
        *flag = (acc == 0u) ? 1 : 0;
    }
}

__device__ __forceinline__ int load_idx(const void* p, int flag, long long i, int limit) {
    int v = flag ? (int)((const long long*)p)[i] : ((const int*)p)[i];
    return min(max(v, 0), limit - 1);   // clamp: garbage -> wrong answer, not crash
}

// graceful fallback if workspace is too small: zero the output, don't touch ws
__global__ __launch_bounds__(256) void zero_out_k(float* __restrict__ out, int n) {
    int i = blockIdx.x * 256 + threadIdx.x;
    if (i < n) out[i] = 0.f;
}

// zero the accumulator region of ws (replaces hipMemsetAsync: keep the launch
// path 100% plain kernel launches for graph-capture safety)
__global__ __launch_bounds__(256) void zero_ws_k(unsigned int* __restrict__ p, long long n) {
    long long i = (long long)blockIdx.x * 256 + threadIdx.x;
    long long stride = (long long)gridDim.x * 256;
    for (; i < n; i += stride) p[i] = 0u;
}

// ---------------- CSR build ----------------

__global__ __launch_bounds__(256) void count_deg(const void* __restrict__ ei, const int* __restrict__ flagp,
                                                 int* __restrict__ cnt) {
    int e = blockIdx.x * 256 + threadIdx.x;
    if (e < NE) atomicAdd(&cnt[load_idx(ei, *flagp, (long long)NE + e, NN)], 1);
}

__global__ __launch_bounds__(256) void scan_partial(const int* __restrict__ cnt, int* __restrict__ bsum) {
    __shared__ int sd[256];
    int t = threadIdx.x;
    int i = blockIdx.x * 256 + t;
    sd[t] = (i < NN) ? cnt[i] : 0;
    __syncthreads();
    for (int st = 128; st > 0; st >>= 1) {
        if (t < st) sd[t] += sd[t + st];
        __syncthreads();
    }
    if (t == 0) bsum[blockIdx.x] = sd[0];
}

__global__ __launch_bounds__(256) void scan_top(int* __restrict__ bsum, int nb) {
    __shared__ int sd[256];
    int t = threadIdx.x;
    int v = (t < nb) ? bsum[t] : 0;
    sd[t] = v;
    __syncthreads();
    for (int st = 1; st < 256; st <<= 1) {
        int a = sd[t];
        int b = (t >= st) ? sd[t - st] : 0;
        __syncthreads();
        sd[t] = a + b;
        __syncthreads();
    }
    if (t < nb) bsum[t] = sd[t] - v;   // exclusive
}

__global__ __launch_bounds__(256) void scan_final(const int* __restrict__ cnt, const int* __restrict__ bsum,
                                                  int* __restrict__ offs, int* __restrict__ curs) {
    __shared__ int sd[256];
    int t = threadIdx.x;
    int i = blockIdx.x * 256 + t;
    int v = (i < NN) ? cnt[i] : 0;
    sd[t] = v;
    __syncthreads();
    for (int st = 1; st < 256; st <<= 1) {
        int a = sd[t];
        int b = (t >= st) ? sd[t - st] : 0;
        __syncthreads();
        sd[t] = a + b;
        __syncthreads();
    }
    int excl = sd[t] - v + bsum[blockIdx.x];
    if (i < NN) { offs[i] = excl; curs[i] = excl; }
}

__global__ __launch_bounds__(256) void fill_csr(const void* __restrict__ ei, const int* __restrict__ flagp,
                                                int* __restrict__ curs, int* __restrict__ elist) {
    int e = blockIdx.x * 256 + threadIdx.x;
    if (e < NE) {
        int p = atomicAdd(&curs[load_idx(ei, *flagp, (long long)NE + e, NN)], 1);
        elist[min(max(p, 0), NE - 1)] = e;
    }
}

// loop_attr[v] = mean of incoming edge_attr (0 if deg==0)
__global__ __launch_bounds__(256) void loop_attr_k(const int* __restrict__ elist, const int* __restrict__ offs,
                                                   const int* __restrict__ cnt, const float* __restrict__ ea,
                                                   float* __restrict__ loopa) {
    int wid = (blockIdx.x * 256 + threadIdx.x) >> 6;
    int lane = threadIdx.x & 63;
    if (wid >= NN) return;
    int o = offs[wid], deg = cnt[wid];
    int f = lane & 31, half = lane >> 5;
    float s = 0.f;
    for (int i = half; i < deg; i += 2) {
        int e = elist[o + i];
        s += ea[(size_t)e * FE + f];
    }
    s += __shfl_down(s, 32);
    if (lane < 32) loopa[(size_t)wid * FE + f] = s / fmaxf((float)deg, 1.f);
}

// ---------------- per-layer node GEMM: xl = h@Wl+bl, xr = h@Wr+br ----------------
// block = 256 threads, 32 rows x 128 cols. xr MAY ALIAS h: each block stages its
// own 32 rows of h into LDS (completed at __syncthreads) before writing those
// same rows of xr; blocks own disjoint row ranges. So h/xr are NOT __restrict__.

__global__ __launch_bounds__(256) void gemm_xlxr(const float* h,
                                                 const float* __restrict__ Wl, const float* __restrict__ bl,
                                                 const float* __restrict__ Wr, const float* __restrict__ br,
                                                 float* __restrict__ xl, float* xr) {
    __shared__ float hs[32][128];
    int tid = threadIdx.x;
    int row0 = blockIdx.x * 32;
    for (int i = tid; i < 1024; i += 256) {        // 1024 float4 = 32x128 floats
        int r = i >> 5, c4 = i & 31;
        int row = row0 + r;
        float4 v = make_float4(0.f, 0.f, 0.f, 0.f);
        if (row < NN) v = reinterpret_cast<const float4*>(h + (size_t)row * DF)[c4];
        reinterpret_cast<float4*>(&hs[r][0])[c4] = v;
    }
    __syncthreads();
    int chalf = tid & 63;            // float2 column index: cols 2*chalf, 2*chalf+1
    int r0 = tid >> 6;               // wave id 0..3 -> rows r0, r0+4, ..., r0+28
    float al0[8] = {}, al1[8] = {}, ar0[8] = {}, ar1[8] = {};
    const float2* Wl2 = reinterpret_cast<const float2*>(Wl);
    const float2* Wr2 = reinterpret_cast<const float2*>(Wr);
    for (int j = 0; j < 128; j += 4) {
        float4 hv[8];
#pragma unroll
        for (int r = 0; r < 8; r++) hv[r] = *reinterpret_cast<const float4*>(&hs[r0 + r * 4][j]);
#pragma unroll
        for (int jj = 0; jj < 4; jj++) {
            float2 wl = Wl2[(j + jj) * 64 + chalf];
            float2 wr = Wr2[(j + jj) * 64 + chalf];
#pragma unroll
            for (int r = 0; r < 8; r++) {
                float hvv = (jj == 0) ? hv[r].x : (jj == 1) ? hv[r].y : (jj == 2) ? hv[r].z : hv[r].w;
                al0[r] += hvv * wl.x; al1[r] += hvv * wl.y;
                ar0[r] += hvv * wr.x; ar1[r] += hvv * wr.y;
            }
        }
    }
    float2 blv = reinterpret_cast<const float2*>(bl)[chalf];
    float2 brv = reinterpret_cast<const float2*>(br)[chalf];
#pragma unroll
    for (int r = 0; r < 8; r++) {
        int row = row0 + r0 + r * 4;
        if (row < NN) {
            reinterpret_cast<float2*>(xl + (size_t)row * DF)[chalf] = make_float2(al0[r] + blv.x, al1[r] + blv.y);
            reinterpret_cast<float2*>(xr + (size_t)row * DF)[chalf] = make_float2(ar0[r] + brv.x, ar1[r] + brv.y);
        }
    }
}

// ---------------- fused edge scoring + online softmax + aggregation ----------------
// one wave per dst node; lane k owns features {2k, 2k+1}; We column-pair in registers.
// hout aliases xr (wave reads only its own xr[v] before writing hout[v]).

__global__ __launch_bounds__(256) void edge_agg(const float* __restrict__ xl, const float* xr,
                                                const void* __restrict__ ei, const int* __restrict__ flagp,
                                                const int* __restrict__ elist, const int* __restrict__ offs,
                                                const int* __restrict__ cnt,
                                                const float* __restrict__ ea, const float* __restrict__ loopa,
                                                const float* __restrict__ We, const float* __restrict__ att,
                                                const float* __restrict__ bias, float* hout) {
    int wid = (blockIdx.x * 256 + threadIdx.x) >> 6;
    int lane = threadIdx.x & 63;
    if (wid >= NN) return;
    int flag = *flagp;
    int v = wid;
    float2 we[32];
#pragma unroll
    for (int j = 0; j < 32; j++) we[j] = reinterpret_cast<const float2*>(We)[j * 64 + lane];
    float2 attv = reinterpret_cast<const float2*>(att)[lane];
    float2 xrv = reinterpret_cast<const float2*>(xr + (size_t)v * DF)[lane];
    float m = -INFINITY, s = 0.f, accx = 0.f, accy = 0.f;
    int o = offs[v], deg = cnt[v];
    // software pipeline: prefetch edge i+1's id/src while processing i
    int e_cur = -1, src_cur = v;
    if (deg > 0) {
        e_cur = elist[o];
        src_cur = load_idx(ei, flag, e_cur, NN);
    }
    for (int i = 0; i <= deg; i++) {     // last iteration = self-loop
        int src = src_cur;
        const float* earow = (i < deg) ? (ea + (size_t)e_cur * FE) : (loopa + (size_t)v * FE);
        // prefetch next
        if (i + 1 < deg) {
            e_cur = elist[o + i + 1];
            src_cur = load_idx(ei, flag, e_cur, NN);
        } else {
            src_cur = v;
        }
        float2 xlv = reinterpret_cast<const float2*>(xl + (size_t)src * DF)[lane];
        float zx0 = xlv.x + xrv.x, zy0 = xlv.y + xrv.y, zx1 = 0.f, zy1 = 0.f;
#pragma unroll
        for (int j4 = 0; j4 < 8; j4++) {
            float4 e4 = reinterpret_cast<const float4*>(earow)[j4];   // broadcast load
            float2 w0 = we[j4 * 4 + 0], w1 = we[j4 * 4 + 1], w2 = we[j4 * 4 + 2], w3 = we[j4 * 4 + 3];
            zx0 += e4.x * w0.x; zy0 += e4.x * w0.y;
            zx1 += e4.y * w1.x; zy1 += e4.y * w1.y;
            zx0 += e4.z * w2.x; zy0 += e4.z * w2.y;
            zx1 += e4.w * w3.x; zy1 += e4.w * w3.y;
        }
        float zx = zx0 + zx1, zy = zy0 + zy1;
        zx = fmaxf(zx, 0.2f * zx);          // leaky_relu(z,0.2) == max(z, 0.2z)
        zy = fmaxf(zy, 0.2f * zy);
        float t = zx * attv.x + zy * attv.y;
#pragma unroll
        for (int d = 1; d < 64; d <<= 1) t += __shfl_xor(t, d);
        float mn = fmaxf(m, t);
        float scale = __expf(m - mn);       // first iter: exp(-inf)=0
        float p = __expf(t - mn);
        s = s * scale + p;
        accx = accx * scale + p * xlv.x;
        accy = accy * scale + p * xlv.y;
        m = mn;
    }
    float2 bv = reinterpret_cast<const float2*>(bias)[lane];
    float inv = 1.f / s;
    float ox = fmaxf(accx * inv + bv.x, 0.f);   // +bias then ReLU
    float oy = fmaxf(accy * inv + bv.y, 0.f);
    reinterpret_cast<float2*>(hout + (size_t)v * DF)[lane] = make_float2(ox, oy);
}

// ---------------- pooling + final linear ----------------

__global__ __launch_bounds__(256) void pool_accum(const float* __restrict__ h, const void* __restrict__ batch,
                                                  const int* __restrict__ flagp,
                                                  float* __restrict__ pooled, int* __restrict__ gcnt) {
    int idx = blockIdx.x * 256 + threadIdx.x;
    if (idx >= NN * DF) return;
    int v = idx >> 7, k = idx & 127;
    int g = load_idx(batch, *flagp, v, NG);
    atomicAdd(&pooled[g * DF + k], h[idx]);
    if (k == 0) atomicAdd(&gcnt[g], 1);
}

__global__ __launch_bounds__(128) void final_lin(const float* __restrict__ pooled, const int* __restrict__ gcnt,
                                                 const float* __restrict__ lw, const float* __restrict__ lb,
                                                 float* __restrict__ out) {
    __shared__ float pr[DF];
    int g = blockIdx.x, t = threadIdx.x;
    float c = fmaxf((float)gcnt[g], 1.f);
    pr[t] = pooled[g * DF + t] / c;
    __syncthreads();
    if (t < NC) {
        float a = lb[t];
        for (int k = 0; k < DF; k++) a += pr[k] * lw[k * NC + t];
        out[g * NC + t] = a;
    }
}

// ---------------- launch ----------------

extern "C" void kernel_launch(void* const* d_in, const int* in_sizes, int n_in,
                              void* d_out, int out_size, void* d_ws, size_t ws_size,
                              hipStream_t stream) {
    const float* x    = (const float*)d_in[0];
    const void*  ei   = d_in[1];               // int32 or int64, detected on device
    const void*  batch= d_in[2];
    const float* ea   = (const float*)d_in[4];
    const float* Wl   = (const float*)d_in[5];
    const float* bl   = (const float*)d_in[6];
    const float* Wr   = (const float*)d_in[7];
    const float* br   = (const float*)d_in[8];
    const float* We   = (const float*)d_in[9];
    const float* att  = (const float*)d_in[10];
    const float* bias = (const float*)d_in[11];
    const float* lw   = (const float*)d_in[12];
    const float* lb   = (const float*)d_in[13];
    float* out = (float*)d_out;

    char* base = (char*)d_ws;
    size_t off = 0;
    auto alloc = [&](size_t bytes) { void* p = base + off; off += (bytes + 255) & ~(size_t)255; return p; };
    float* XL    = (float*)alloc((size_t)NN * DF * 4);   // 25.6 MB
    float* B1    = (float*)alloc((size_t)NN * DF * 4);   // 25.6 MB (xr / hout / next hin, in place)
    float* LOOPA = (float*)alloc((size_t)NN * FE * 4);   // 6.4 MB
    int*   ELIST = (int*)alloc((size_t)NE * 4);          // 6.4 MB
    int*   OFFS  = (int*)alloc((size_t)NN * 4);
    int*   CURS  = (int*)alloc((size_t)NN * 4);
    int*   BSUM  = (int*)alloc(256 * 4);
    int*   IFLAG = (int*)alloc(256);
    // contiguous zero region (ws is poisoned 0xAA before every timed call)
    char*  zbase = base + off;
    int*   CNT   = (int*)alloc((size_t)NN * 4);
    int*   GCNT  = (int*)alloc(NG * 4);
    float* POOL  = (float*)alloc((size_t)NG * DF * 4);
    size_t zbytes = (size_t)((char*)(POOL + NG * DF) - zbase);
    size_t needed = off;

    if (ws_size < needed) {
        // not enough scratch: produce a deterministic (wrong) output instead of
        // faulting the container; diagnosable via validation failure.
        zero_out_k<<<(out_size + 255) / 256, 256, 0, stream>>>(out, out_size);
        return;
    }
    // zero accumulators with a plain kernel (launch path = kernel launches only)
    zero_ws_k<<<512, 256, 0, stream>>>((unsigned int*)zbase, (long long)(zbytes / 4));

    int nb = (NN + 255) / 256;   // 196
    detect_i64 <<<1, 64, 0, stream>>>((const unsigned int*)ei, IFLAG);
    count_deg  <<<NE / 256, 256, 0, stream>>>(ei, IFLAG, CNT);
    scan_partial<<<nb, 256, 0, stream>>>(CNT, BSUM);
    scan_top   <<<1, 256, 0, stream>>>(BSUM, nb);
    scan_final <<<nb, 256, 0, stream>>>(CNT, BSUM, OFFS, CURS);
    fill_csr   <<<NE / 256, 256, 0, stream>>>(ei, IFLAG, CURS, ELIST);
    loop_attr_k<<<(NN + 3) / 4, 256, 0, stream>>>(ELIST, OFFS, CNT, ea, LOOPA);

    // layer 0: hin = x (read-only), xr -> B1, agg in-place into B1
    // layers 1,2: hin = B1; gemm writes xr in-place over B1 (block-local rows);
    //             agg in-place into B1 again.
    const float* hin = x;
    for (int l = 0; l < 3; l++) {
        gemm_xlxr<<<(NN + 31) / 32, 256, 0, stream>>>(hin, Wl + l * DF * DF, bl + l * DF,
                                                      Wr + l * DF * DF, br + l * DF, XL, B1);
        edge_agg <<<(NN + 3) / 4, 256, 0, stream>>>(XL, B1, ei, IFLAG, ELIST, OFFS, CNT, ea, LOOPA,
                                                    We + l * FE * DF, att + l * DF, bias + l * DF, B1);
        hin = B1;
    }
    pool_accum<<<(NN * DF) / 256, 256, 0, stream>>>(hin, batch, IFLAG, POOL, GCNT);
    final_lin <<<NG, DF, 0, stream>>>(POOL, GCNT, lw, lb, out);
}

// Round 5
// 3667.108 us; speedup vs baseline: 2.5479x; 2.5479x over previous
//
#include <hip/hip_runtime.h>
#include <math.h>

#define NN 50000
#define NE 1600000
#define FE 32
#define DF 128
#define NG 512
#define NC 10
#define GR 64   // rows per gemm block

// ---------------- int64-vs-int32 index dtype detection ----------------

__global__ void detect_i64(const unsigned int* __restrict__ w, int* __restrict__ flag) {
    if (threadIdx.x == 0 && blockIdx.x == 0) {
        unsigned int acc = 0;
        for (int i = 0; i < 128; i++) acc |= w[2 * i + 1];
        *flag = (acc == 0u) ? 1 : 0;
    }
}

__device__ __forceinline__ int load_idx(const void* p, int flag, long long i, int limit) {
    int v = flag ? (int)((const long long*)p)[i] : ((const int*)p)[i];
    return min(max(v, 0), limit - 1);   // clamp: garbage -> wrong answer, not crash
}

// graceful fallback if workspace is too small
__global__ __launch_bounds__(256) void zero_out_k(float* __restrict__ out, int n) {
    int i = blockIdx.x * 256 + threadIdx.x;
    if (i < n) out[i] = 0.f;
}

// zero the accumulator region of ws (plain kernel: graph-capture safe)
__global__ __launch_bounds__(256) void zero_ws_k(unsigned int* __restrict__ p, long long n) {
    long long i = (long long)blockIdx.x * 256 + threadIdx.x;
    long long stride = (long long)gridDim.x * 256;
    for (; i < n; i += stride) p[i] = 0u;
}

// ---------------- CSR build ----------------

__global__ __launch_bounds__(256) void count_deg(const void* __restrict__ ei, const int* __restrict__ flagp,
                                                 int* __restrict__ cnt) {
    int e = blockIdx.x * 256 + threadIdx.x;
    if (e < NE) atomicAdd(&cnt[load_idx(ei, *flagp, (long long)NE + e, NN)], 1);
}

__global__ __launch_bounds__(256) void scan_partial(const int* __restrict__ cnt, int* __restrict__ bsum) {
    __shared__ int sd[256];
    int t = threadIdx.x;
    int i = blockIdx.x * 256 + t;
    sd[t] = (i < NN) ? cnt[i] : 0;
    __syncthreads();
    for (int st = 128; st > 0; st >>= 1) {
        if (t < st) sd[t] += sd[t + st];
        __syncthreads();
    }
    if (t == 0) bsum[blockIdx.x] = sd[0];
}

__global__ __launch_bounds__(256) void scan_top(int* __restrict__ bsum, int nb) {
    __shared__ int sd[256];
    int t = threadIdx.x;
    int v = (t < nb) ? bsum[t] : 0;
    sd[t] = v;
    __syncthreads();
    for (int st = 1; st < 256; st <<= 1) {
        int a = sd[t];
        int b = (t >= st) ? sd[t - st] : 0;
        __syncthreads();
        sd[t] = a + b;
        __syncthreads();
    }
    if (t < nb) bsum[t] = sd[t] - v;   // exclusive
}

__global__ __launch_bounds__(256) void scan_final(const int* __restrict__ cnt, const int* __restrict__ bsum,
                                                  int* __restrict__ offs, int* __restrict__ curs) {
    __shared__ int sd[256];
    int t = threadIdx.x;
    int i = blockIdx.x * 256 + t;
    int v = (i < NN) ? cnt[i] : 0;
    sd[t] = v;
    __syncthreads();
    for (int st = 1; st < 256; st <<= 1) {
        int a = sd[t];
        int b = (t >= st) ? sd[t - st] : 0;
        __syncthreads();
        sd[t] = a + b;
        __syncthreads();
    }
    int excl = sd[t] - v + bsum[blockIdx.x];
    if (i < NN) { offs[i] = excl; curs[i] = excl; }
}

__global__ __launch_bounds__(256) void fill_csr(const void* __restrict__ ei, const int* __restrict__ flagp,
                                                int* __restrict__ curs, int* __restrict__ elist) {
    int e = blockIdx.x * 256 + threadIdx.x;
    if (e < NE) {
        int p = atomicAdd(&curs[load_idx(ei, *flagp, (long long)NE + e, NN)], 1);
        elist[min(max(p, 0), NE - 1)] = e;
    }
}

// loop_attr[v] = mean of incoming edge_attr (0 if deg==0)
__global__ __launch_bounds__(256) void loop_attr_k(const int* __restrict__ elist, const int* __restrict__ offs,
                                                   const int* __restrict__ cnt, const float* __restrict__ ea,
                                                   float* __restrict__ loopa) {
    int wid = (blockIdx.x * 256 + threadIdx.x) >> 6;
    int lane = threadIdx.x & 63;
    if (wid >= NN) return;
    int o = offs[wid], deg = cnt[wid];
    int f = lane & 31, half = lane >> 5;
    float s = 0.f;
    for (int i = half; i < deg; i += 2) {
        int e = elist[o + i];
        s += ea[(size_t)e * FE + f];
    }
    s += __shfl_down(s, 32);
    if (lane < 32) loopa[(size_t)wid * FE + f] = s / fmaxf((float)deg, 1.f);
}

// ---------------- per-layer node GEMM: xl = h@Wl+bl, xr = h@Wr+br ----------------
// LDS-staged tile GEMM. Block = 256 threads = 16x16; 64 rows x all 256 out cols.
// hsT: k-major h tile with XOR swizzle col = r ^ (k&60): conflict-free float4
// reads (a), 4-way staging writes. wst: k-major weight tile [128][64], 2-way (free).
// No global loads in the K-loop -> no spill pressure (round-4 bug: 256 VGPR,
// 1.76GB fetch / 1.52GB write per dispatch = scratch round-trips).
// xr MAY ALIAS h: block stages its own 64 rows before first sync; writes only
// those rows. Blocks own disjoint rows. So h/xr NOT __restrict__.

__global__ __launch_bounds__(256, 2) void gemm_xlxr(const float* h,
                                                    const float* __restrict__ Wl, const float* __restrict__ bl,
                                                    const float* __restrict__ Wr, const float* __restrict__ br,
                                                    float* __restrict__ xl, float* xr) {
    __shared__ float hsT[DF * GR];   // [k][c], c = r ^ (k & 60)   32 KB
    __shared__ float wst[DF * GR];   // [k][col] current 64-col tile 32 KB
    int tid = threadIdx.x;
    int row0 = blockIdx.x * GR;

    // stage hsT (transposed + swizzled)
    for (int it = 0; it < 8; ++it) {
        int idx = it * 256 + tid;        // 0..2047
        int r = idx >> 5;                // 0..63
        int k4 = idx & 31;               // float4 index along k
        int row = row0 + r;
        float4 v = make_float4(0.f, 0.f, 0.f, 0.f);
        if (row < NN) v = reinterpret_cast<const float4*>(h + (size_t)row * DF)[k4];
        int k = k4 * 4;
        int c = r ^ (k & 60);            // (k+i)&60 == k&60 for i<4
        hsT[(k + 0) * GR + c] = v.x;
        hsT[(k + 1) * GR + c] = v.y;
        hsT[(k + 2) * GR + c] = v.z;
        hsT[(k + 3) * GR + c] = v.w;
    }

    int ty4 = (tid >> 4) * 4;            // row within tile: ty4..ty4+3
    int tx4 = (tid & 15) * 4;            // col within 64-col tile

    for (int ct = 0; ct < 4; ++ct) {     // 0,1: Wl cols 0-63,64-127; 2,3: Wr
        const float* Wsrc = (ct < 2) ? Wl : Wr;
        const float* bsrc = (ct < 2) ? bl : br;
        float* osrc = (ct < 2) ? xl : xr;
        int c0 = (ct & 1) * 64;

        __syncthreads();                 // hsT ready (ct=0) / prev compute done
        for (int it = 0; it < 8; ++it) {
            int idx = it * 256 + tid;    // 0..2047
            int k = idx >> 4;            // 0..127
            int j4 = (idx & 15) * 4;     // 0..60
            float4 w = *reinterpret_cast<const float4*>(&Wsrc[(size_t)k * DF + c0 + j4]);
            *reinterpret_cast<float4*>(&wst[k * GR + j4]) = w;
        }
        __syncthreads();

        float acc[4][4] = {};
#pragma unroll 4
        for (int k = 0; k < DF; ++k) {
            float4 a = *reinterpret_cast<const float4*>(&hsT[k * GR + (ty4 ^ (k & 60))]);
            float4 b = *reinterpret_cast<const float4*>(&wst[k * GR + tx4]);
            acc[0][0] += a.x * b.x; acc[0][1] += a.x * b.y; acc[0][2] += a.x * b.z; acc[0][3] += a.x * b.w;
            acc[1][0] += a.y * b.x; acc[1][1] += a.y * b.y; acc[1][2] += a.y * b.z; acc[1][3] += a.y * b.w;
            acc[2][0] += a.z * b.x; acc[2][1] += a.z * b.y; acc[2][2] += a.z * b.z; acc[2][3] += a.z * b.w;
            acc[3][0] += a.w * b.x; acc[3][1] += a.w * b.y; acc[3][2] += a.w * b.z; acc[3][3] += a.w * b.w;
        }

        float4 bv = *reinterpret_cast<const float4*>(&bsrc[c0 + tx4]);
#pragma unroll
        for (int i = 0; i < 4; ++i) {
            int row = row0 + ty4 + i;
            if (row < NN) {
                float4 o = make_float4(acc[i][0] + bv.x, acc[i][1] + bv.y,
                                       acc[i][2] + bv.z, acc[i][3] + bv.w);
                *reinterpret_cast<float4*>(&osrc[(size_t)row * DF + c0 + tx4]) = o;
            }
        }
    }
}

// ---------------- fused edge scoring + online softmax + aggregation ----------------
// one wave per dst node; lane k owns features {2k, 2k+1}; We column-pair in registers.
// hout aliases xr (wave reads only its own xr[v] before writing hout[v]).

__global__ __launch_bounds__(256) void edge_agg(const float* __restrict__ xl, const float* xr,
                                                const void* __restrict__ ei, const int* __restrict__ flagp,
                                                const int* __restrict__ elist, const int* __restrict__ offs,
                                                const int* __restrict__ cnt,
                                                const float* __restrict__ ea, const float* __restrict__ loopa,
                                                const float* __restrict__ We, const float* __restrict__ att,
                                                const float* __restrict__ bias, float* hout) {
    int wid = (blockIdx.x * 256 + threadIdx.x) >> 6;
    int lane = threadIdx.x & 63;
    if (wid >= NN) return;
    int flag = *flagp;
    int v = wid;
    float2 we[32];
#pragma unroll
    for (int j = 0; j < 32; j++) we[j] = reinterpret_cast<const float2*>(We)[j * 64 + lane];
    float2 attv = reinterpret_cast<const float2*>(att)[lane];
    float2 xrv = reinterpret_cast<const float2*>(xr + (size_t)v * DF)[lane];
    float m = -INFINITY, s = 0.f, accx = 0.f, accy = 0.f;
    int o = offs[v], deg = cnt[v];
    int e_cur = -1, src_cur = v;
    if (deg > 0) {
        e_cur = elist[o];
        src_cur = load_idx(ei, flag, e_cur, NN);
    }
    for (int i = 0; i <= deg; i++) {     // last iteration = self-loop
        int src = src_cur;
        const float* earow = (i < deg) ? (ea + (size_t)e_cur * FE) : (loopa + (size_t)v * FE);
        if (i + 1 < deg) {
            e_cur = elist[o + i + 1];
            src_cur = load_idx(ei, flag, e_cur, NN);
        } else {
            src_cur = v;
        }
        float2 xlv = reinterpret_cast<const float2*>(xl + (size_t)src * DF)[lane];
        float zx0 = xlv.x + xrv.x, zy0 = xlv.y + xrv.y, zx1 = 0.f, zy1 = 0.f;
#pragma unroll
        for (int j4 = 0; j4 < 8; j4++) {
            float4 e4 = reinterpret_cast<const float4*>(earow)[j4];   // broadcast load
            float2 w0 = we[j4 * 4 + 0], w1 = we[j4 * 4 + 1], w2 = we[j4 * 4 + 2], w3 = we[j4 * 4 + 3];
            zx0 += e4.x * w0.x; zy0 += e4.x * w0.y;
            zx1 += e4.y * w1.x; zy1 += e4.y * w1.y;
            zx0 += e4.z * w2.x; zy0 += e4.z * w2.y;
            zx1 += e4.w * w3.x; zy1 += e4.w * w3.y;
        }
        float zx = zx0 + zx1, zy = zy0 + zy1;
        zx = fmaxf(zx, 0.2f * zx);          // leaky_relu
        zy = fmaxf(zy, 0.2f * zy);
        float t = zx * attv.x + zy * attv.y;
#pragma unroll
        for (int d = 1; d < 64; d <<= 1) t += __shfl_xor(t, d);
        float mn = fmaxf(m, t);
        float scale = __expf(m - mn);       // first iter: exp(-inf)=0
        float p = __expf(t - mn);
        s = s * scale + p;
        accx = accx * scale + p * xlv.x;
        accy = accy * scale + p * xlv.y;
        m = mn;
    }
    float2 bv = reinterpret_cast<const float2*>(bias)[lane];
    float inv = 1.f / s;
    float ox = fmaxf(accx * inv + bv.x, 0.f);   // +bias then ReLU
    float oy = fmaxf(accy * inv + bv.y, 0.f);
    reinterpret_cast<float2*>(hout + (size_t)v * DF)[lane] = make_float2(ox, oy);
}

// ---------------- pooling + final linear ----------------

__global__ __launch_bounds__(256) void pool_accum(const float* __restrict__ h, const void* __restrict__ batch,
                                                  const int* __restrict__ flagp,
                                                  float* __restrict__ pooled, int* __restrict__ gcnt) {
    int idx = blockIdx.x * 256 + threadIdx.x;
    if (idx >= NN * DF) return;
    int v = idx >> 7, k = idx & 127;
    int g = load_idx(batch, *flagp, v, NG);
    atomicAdd(&pooled[g * DF + k], h[idx]);
    if (k == 0) atomicAdd(&gcnt[g], 1);
}

__global__ __launch_bounds__(128) void final_lin(const float* __restrict__ pooled, const int* __restrict__ gcnt,
                                                 const float* __restrict__ lw, const float* __restrict__ lb,
                                                 float* __restrict__ out) {
    __shared__ float pr[DF];
    int g = blockIdx.x, t = threadIdx.x;
    float c = fmaxf((float)gcnt[g], 1.f);
    pr[t] = pooled[g * DF + t] / c;
    __syncthreads();
    if (t < NC) {
        float a = lb[t];
        for (int k = 0; k < DF; k++) a += pr[k] * lw[k * NC + t];
        out[g * NC + t] = a;
    }
}

// ---------------- launch ----------------

extern "C" void kernel_launch(void* const* d_in, const int* in_sizes, int n_in,
                              void* d_out, int out_size, void* d_ws, size_t ws_size,
                              hipStream_t stream) {
    const float* x    = (const float*)d_in[0];
    const void*  ei   = d_in[1];               // int32 or int64, detected on device
    const void*  batch= d_in[2];
    const float* ea   = (const float*)d_in[4];
    const float* Wl   = (const float*)d_in[5];
    const float* bl   = (const float*)d_in[6];
    const float* Wr   = (const float*)d_in[7];
    const float* br   = (const float*)d_in[8];
    const float* We   = (const float*)d_in[9];
    const float* att  = (const float*)d_in[10];
    const float* bias = (const float*)d_in[11];
    const float* lw   = (const float*)d_in[12];
    const float* lb   = (const float*)d_in[13];
    float* out = (float*)d_out;

    char* base = (char*)d_ws;
    size_t off = 0;
    auto alloc = [&](size_t bytes) { void* p = base + off; off += (bytes + 255) & ~(size_t)255; return p; };
    float* XL    = (float*)alloc((size_t)NN * DF * 4);   // 25.6 MB
    float* B1    = (float*)alloc((size_t)NN * DF * 4);   // 25.6 MB (xr / hout / next hin, in place)
    float* LOOPA = (float*)alloc((size_t)NN * FE * 4);   // 6.4 MB
    int*   ELIST = (int*)alloc((size_t)NE * 4);          // 6.4 MB
    int*   OFFS  = (int*)alloc((size_t)NN * 4);
    int*   CURS  = (int*)alloc((size_t)NN * 4);
    int*   BSUM  = (int*)alloc(256 * 4);
    int*   IFLAG = (int*)alloc(256);
    // contiguous zero region (ws is poisoned 0xAA before every timed call)
    char*  zbase = base + off;
    int*   CNT   = (int*)alloc((size_t)NN * 4);
    int*   GCNT  = (int*)alloc(NG * 4);
    float* POOL  = (float*)alloc((size_t)NG * DF * 4);
    size_t zbytes = (size_t)((char*)(POOL + NG * DF) - zbase);
    size_t needed = off;

    if (ws_size < needed) {
        zero_out_k<<<(out_size + 255) / 256, 256, 0, stream>>>(out, out_size);
        return;
    }
    zero_ws_k<<<512, 256, 0, stream>>>((unsigned int*)zbase, (long long)(zbytes / 4));

    int nb = (NN + 255) / 256;   // 196
    detect_i64 <<<1, 64, 0, stream>>>((const unsigned int*)ei, IFLAG);
    count_deg  <<<NE / 256, 256, 0, stream>>>(ei, IFLAG, CNT);
    scan_partial<<<nb, 256, 0, stream>>>(CNT, BSUM);
    scan_top   <<<1, 256, 0, stream>>>(BSUM, nb);
    scan_final <<<nb, 256, 0, stream>>>(CNT, BSUM, OFFS, CURS);
    fill_csr   <<<NE / 256, 256, 0, stream>>>(ei, IFLAG, CURS, ELIST);
    loop_attr_k<<<(NN + 3) / 4, 256, 0, stream>>>(ELIST, OFFS, CNT, ea, LOOPA);

    const float* hin = x;
    for (int l = 0; l < 3; l++) {
        gemm_xlxr<<<(NN + GR - 1) / GR, 256, 0, stream>>>(hin, Wl + l * DF * DF, bl + l * DF,
                                                          Wr + l * DF * DF, br + l * DF, XL, B1);
        edge_agg <<<(NN + 3) / 4, 256, 0, stream>>>(XL, B1, ei, IFLAG, ELIST, OFFS, CNT, ea, LOOPA,
                                                    We + l * FE * DF, att + l * DF, bias + l * DF, B1);
        hin = B1;
    }
    pool_accum<<<(NN * DF) / 256, 256, 0, stream>>>(hin, batch, IFLAG, POOL, GCNT);
    final_lin <<<NG, DF, 0, stream>>>(POOL, GCNT, lw, lb, out);
}